// Round 16
// baseline (2248.332 us; speedup 1.0000x reference)
//
#include <hip/hip_runtime.h>
#include <hip/hip_fp16.h>

constexpr int N_USERS = 50000;
constexpr int N_ENT   = 100000;
constexpr int N_NODES = 150000;
constexpr int N_EDGES = 2400000;
constexpr int OUT_D   = 176;               // 64 + 64 + 32 + 16

constexpr int RPB       = 293;             // rows per bucket
constexpr int NBKT      = 512;             // buckets (= fused grid, 2/CU)
constexpr int P1_BLOCKS = 293;             // pass-1 chunks
constexpr int CHUNK     = 8192;            // edges per pass-1 chunk
constexpr int TBL       = NBKT * P1_BLOCKS;            // 150016
constexpr int SCAN_BLKS = (TBL + 1023) / 1024;         // 147

// ws layout (bytes):
//   tmp u64[2.4M] @0 (19.2MB)  -- CSR temp; after CSR: xq int8[N][64] @0
//     (9.6MB) | xs float[N] @9,600,000 (0.6MB)
//   edges u32 @19,200,000 (9.6MB)   (col<<14 | val14, col-sorted per bucket)
//   rowLs u16 @28,800,000 (4.8MB)   (rowLocal per edge)
//   table int[TBL] @33,600,000 (600KB) | bsum @34,300,000 (588B)
//   WT __half[13312] @34,400,000 (26.6KB)              = ~34.43MB

typedef _Float16 h2v __attribute__((ext_vector_type(2)));
union H2U { unsigned u; h2v v; };

__device__ inline float dot2(unsigned a, unsigned b, float c) {
    H2U x, y; x.u = a; y.u = b;
    return __builtin_amdgcn_fdot2(x.v, y.v, c, false);
}

// ---------------------------------------------------------------------------
// init: out[:,0:64) = concat(ue,ee)
// ---------------------------------------------------------------------------
__global__ __launch_bounds__(256) void init_x_kernel(const float* __restrict__ ue,
                                                     const float* __restrict__ ee,
                                                     float* __restrict__ out) {
    int tid = blockIdx.x * 256 + threadIdx.x;    // N_NODES * 16 float4s
    int n = tid >> 4, q = tid & 15;
    const float* src = (n < N_USERS) ? ue + (size_t)n * 64
                                     : ee + (size_t)(n - N_USERS) * 64;
    float4 v = *(const float4*)(src + q * 4);
    *(float4*)(out + (size_t)n * OUT_D + q * 4) = v;
}

// ---------------------------------------------------------------------------
// quant: fp32 slab cols -> int8 rows (per-row max scale). din4 = DIN/4.
// ---------------------------------------------------------------------------
__global__ __launch_bounds__(256) void quant_kernel(const float* __restrict__ src,
                                                    signed char* __restrict__ xq,
                                                    float* __restrict__ xs,
                                                    int din4) {
    int tid = blockIdx.x * 256 + threadIdx.x;
    int n = tid / din4, t = tid % din4;
    if (n >= N_NODES) return;
    float4 v = *(const float4*)(src + (size_t)n * OUT_D + 4 * t);
    float m = fmaxf(fmaxf(fabsf(v.x), fabsf(v.y)), fmaxf(fabsf(v.z), fabsf(v.w)));
    for (int off = din4 >> 1; off; off >>= 1) m = fmaxf(m, __shfl_xor(m, off));
    float inv = 127.f / (m + 1e-20f);
    int q0 = __float2int_rn(v.x * inv);
    int q1 = __float2int_rn(v.y * inv);
    int q2 = __float2int_rn(v.z * inv);
    int q3 = __float2int_rn(v.w * inv);
    unsigned pk = (q0 & 0xFF) | ((q1 & 0xFF) << 8) | ((q2 & 0xFF) << 16) | ((q3 & 0xFF) << 24);
    *(unsigned*)(xq + (size_t)n * (din4 * 4) + 4 * t) = pk;
    if (t == 0) xs[n] = (m + 1e-20f) * (1.f / 127.f);
}

// ---------------------------------------------------------------------------
// Weights, fp16, k-interleaved: dest[base + (i/8)*DOUT*8 + o*8 + (i%8)]
// ---------------------------------------------------------------------------
__global__ __launch_bounds__(256) void wt_kernel(const float* __restrict__ Wg0,
                                                 const float* __restrict__ Wb0,
                                                 const float* __restrict__ Wg1,
                                                 const float* __restrict__ Wb1,
                                                 const float* __restrict__ Wg2,
                                                 const float* __restrict__ Wb2,
                                                 __half* __restrict__ WT) {
    int idx = blockIdx.x * 256 + threadIdx.x;   // 52*256 == 13312
    const float* src; int dout, base;
    if (idx < 8192)       { base = (idx < 4096) ? 0 : 4096;
                            src  = (idx < 4096) ? Wg0 : Wb0;  dout = 64; }
    else if (idx < 12288) { base = (idx < 10240) ? 8192 : 10240;
                            src  = (idx < 10240) ? Wg1 : Wb1; dout = 32; }
    else                  { base = (idx < 12800) ? 12288 : 12800;
                            src  = (idx < 12800) ? Wg2 : Wb2; dout = 16; }
    int r = idx - base;
    int i = r / dout, o = r % dout;
    int dest = base + (i / 8) * dout * 8 + o * 8 + (i % 8);
    WT[dest] = __float2half(src[r]);
}

// ---------------------------------------------------------------------------
// Pass 1: partition edges by row bucket (row / 293), 512 buckets.
// ---------------------------------------------------------------------------
__global__ __launch_bounds__(256) void histP1_kernel(const int* __restrict__ er,
                                                     int* __restrict__ table) {
    __shared__ int h[NBKT];
    for (int i = threadIdx.x; i < NBKT; i += 256) h[i] = 0;
    __syncthreads();
    int base = blockIdx.x * CHUNK;
    for (int i = threadIdx.x; i < CHUNK; i += 256) {
        int e = base + i;
        if (e < N_EDGES) atomicAdd(&h[er[e] / RPB], 1);
    }
    __syncthreads();
    for (int i = threadIdx.x; i < NBKT; i += 256)
        table[i * P1_BLOCKS + blockIdx.x] = h[i];
}

__global__ __launch_bounds__(1024) void scanA_kernel(const int* __restrict__ a,
                                                     int* __restrict__ bsum, int n) {
    __shared__ int wsum[16];
    int i = blockIdx.x * 1024 + threadIdx.x;
    int v = (i < n) ? a[i] : 0;
    #pragma unroll
    for (int off = 32; off; off >>= 1) v += __shfl_xor(v, off);
    int lane = threadIdx.x & 63, w = threadIdx.x >> 6;
    if (lane == 0) wsum[w] = v;
    __syncthreads();
    if (threadIdx.x == 0) {
        int t = 0;
        #pragma unroll
        for (int k = 0; k < 16; ++k) t += wsum[k];
        bsum[blockIdx.x] = t;
    }
}

__global__ __launch_bounds__(1024) void scanB_kernel(int* __restrict__ bsum, int n) {
    __shared__ int wtot[16];
    __shared__ int carry_s;
    int tid = threadIdx.x;
    int lane = tid & 63, w = tid >> 6;
    if (tid == 0) carry_s = 0;
    __syncthreads();
    for (int base = 0; base < n; base += 1024) {
        int i = base + tid;
        int v = (i < n) ? bsum[i] : 0;
        int incl = v;
        #pragma unroll
        for (int off = 1; off < 64; off <<= 1) {
            int t = __shfl_up(incl, off);
            if (lane >= off) incl += t;
        }
        if (lane == 63) wtot[w] = incl;
        __syncthreads();
        int woff = 0, total = 0;
        #pragma unroll
        for (int k = 0; k < 16; ++k) {
            int tk = wtot[k];
            if (k < w) woff += tk;
            total += tk;
        }
        if (i < n) bsum[i] = carry_s + woff + incl - v;
        __syncthreads();
        if (tid == 0) carry_s += total;
        __syncthreads();
    }
}

__global__ __launch_bounds__(1024) void scanC_kernel(int* __restrict__ a,
                                                     const int* __restrict__ bsum, int n) {
    __shared__ int wtot[16];
    int i = blockIdx.x * 1024 + threadIdx.x;
    int lane = threadIdx.x & 63, w = threadIdx.x >> 6;
    int v = (i < n) ? a[i] : 0;
    int incl = v;
    #pragma unroll
    for (int off = 1; off < 64; off <<= 1) {
        int t = __shfl_up(incl, off);
        if (lane >= off) incl += t;
    }
    if (lane == 63) wtot[w] = incl;
    __syncthreads();
    int woff = 0;
    #pragma unroll
    for (int k = 0; k < 16; ++k) if (k < w) woff += wtot[k];
    if (i < n) a[i] = bsum[blockIdx.x] + woff + incl - v;
}

// Pass-1 scatter: rec = rowLocal<<32 | col<<14 | val14, bucket-grouped.
__global__ __launch_bounds__(256) void scatterP1_kernel(const float* __restrict__ ev,
                                                        const int*   __restrict__ er,
                                                        const int*   __restrict__ ec,
                                                        const int*   __restrict__ table,
                                                        unsigned long long* __restrict__ tmp) {
    __shared__ int lcur[NBKT];
    for (int i = threadIdx.x; i < NBKT; i += 256)
        lcur[i] = table[i * P1_BLOCKS + blockIdx.x];
    __syncthreads();
    int base = blockIdx.x * CHUNK;
    for (int i = threadIdx.x; i < CHUNK; i += 256) {
        int e = base + i;
        if (e < N_EDGES) {
            int r = er[e], c = ec[e];
            int bkt = r / RPB;
            int rl = r - bkt * RPB;
            int v14 = (int)(ev[e] * 16384.0f + 0.5f);
            v14 = v14 > 16383 ? 16383 : v14;
            int pos = atomicAdd(&lcur[bkt], 1);
            tmp[pos] = ((unsigned long long)rl << 32)
                     | ((unsigned)c << 14) | (unsigned)v14;
        }
    }
}

// Pass 2: per bucket, sort edges by col>>9 (293 col-blocks) -> edges/rowLs.
__global__ __launch_bounds__(512) void pass2_kernel(const unsigned long long* __restrict__ tmp,
                                                    const int* __restrict__ table,
                                                    unsigned* __restrict__ edges,
                                                    unsigned short* __restrict__ rowLs) {
    __shared__ int hcnt[512];
    __shared__ int sinc[512];
    __shared__ int scur[512];
    int b = blockIdx.x;
    int tid = threadIdx.x;
    int eStart = table[b * P1_BLOCKS];
    int eEnd = (b + 1 < NBKT) ? table[(b + 1) * P1_BLOCKS] : N_EDGES;

    hcnt[tid] = 0;
    __syncthreads();
    for (int e = eStart + tid; e < eEnd; e += 512) {
        unsigned cb = ((unsigned)tmp[e]) >> 23;     // col>>9, 0..292
        atomicAdd(&hcnt[cb], 1);
    }
    __syncthreads();
    sinc[tid] = hcnt[tid];
    __syncthreads();
    #pragma unroll
    for (int off = 1; off < 512; off <<= 1) {
        int t = (tid >= off) ? sinc[tid - off] : 0;
        __syncthreads();
        sinc[tid] += t;
        __syncthreads();
    }
    scur[tid] = eStart + sinc[tid] - hcnt[tid];     // exclusive start
    __syncthreads();
    for (int e = eStart + tid; e < eEnd; e += 512) {
        unsigned long long rec = tmp[e];
        unsigned lo = (unsigned)rec;
        int pos = atomicAdd(&scur[lo >> 23], 1);
        edges[pos] = lo;
        rowLs[pos] = (unsigned short)(rec >> 32);
    }
}

// ---------------------------------------------------------------------------
// Fused layer V2: column-swept SpMM with LDS side accumulator + dense epilogue.
// Grid = 512 blocks (2/CU), block = 512 threads (8 waves).
// Each block owns 293 rows; edges sorted by column -> all concurrent blocks
// sweep xq (int8, 9.6MB) in the same order -> XCD-L2 hits by construction.
// ---------------------------------------------------------------------------
template<int DIN, int DOUT>
__global__ __launch_bounds__(512, 4) void fusedv2_kernel(
        const int*            __restrict__ table,
        const unsigned*       __restrict__ edges,
        const unsigned short* __restrict__ rowLs,
        const signed char*    __restrict__ xq,
        const float*          __restrict__ xs,
        float* __restrict__ out,
        const __half* __restrict__ WT, int wgOff, int wbOff,
        const float* __restrict__ bgc, const float* __restrict__ bbi,
        int cin, int cout) {
    __shared__ float side[RPB * DIN];
    __shared__ unsigned ash[8][DIN / 2];
    __shared__ unsigned bsh[8][DIN / 2];

    int b = blockIdx.x, tid = threadIdx.x;
    int eStart = table[b * P1_BLOCKS];
    int eEnd = (b + 1 < NBKT) ? table[(b + 1) * P1_BLOCKS] : N_EDGES;

    for (int i = tid; i < RPB * DIN; i += 512) side[i] = 0.f;
    __syncthreads();

    constexpr int QP = DIN / 4;          // lanes per edge (16 or 8)
    constexpr int EPC = 512 / QP;        // edges per chunk (32 or 64)
    int g = tid / QP;
    int t = tid % QP;
    const unsigned* xqw = (const unsigned*)xq;

    for (int e0 = eStart; e0 < eEnd; e0 += 4 * EPC) {
        unsigned rec[4]; int rl[4];
        #pragma unroll
        for (int j = 0; j < 4; ++j) {
            int idx = e0 + j * EPC + g;
            unsigned r = edges[idx];               // unguarded: ws-mapped
            unsigned short rr = rowLs[idx];        // unguarded: ws-mapped
            bool ok = idx < eEnd;
            rec[j] = ok ? r : 0u;
            rl[j]  = ok ? (int)rr : 0;
        }
        unsigned q[4]; float f[4];
        #pragma unroll
        for (int j = 0; j < 4; ++j) {
            unsigned col = rec[j] >> 14;
            q[j] = xqw[(size_t)col * QP + t];
            f[j] = (float)(rec[j] & 16383u) * (1.0f / 16384.0f) * xs[col];
        }
        #pragma unroll
        for (int j = 0; j < 4; ++j) {
            float* sp = &side[rl[j] * DIN + 4 * t];
            unsigned qq = q[j];
            atomicAdd(sp + 0, f[j] * (float)(int)(signed char)(qq & 0xFF));
            atomicAdd(sp + 1, f[j] * (float)(int)(signed char)((qq >> 8) & 0xFF));
            atomicAdd(sp + 2, f[j] * (float)(int)(signed char)((qq >> 16) & 0xFF));
            atomicAdd(sp + 3, f[j] * (float)(int)(signed char)(qq >> 24));
        }
    }
    __syncthreads();

    // ---- dense epilogue: 293 rows over 8 waves ----
    int w = tid >> 6, lane = tid & 63;

    // weights to registers once
    uint4 wg[DIN / 8], wb[DIN / 8];
    if constexpr (DOUT == DIN) {
        int o = lane;
        #pragma unroll
        for (int k = 0; k < DIN / 8; ++k) {
            wg[k] = *(const uint4*)(WT + wgOff + (size_t)(k * DOUT + o) * 8);
            wb[k] = *(const uint4*)(WT + wbOff + (size_t)(k * DOUT + o) * 8);
        }
    } else {
        int o = lane & (DOUT - 1);
        bool gc = lane < DOUT;
        int woff2 = gc ? wgOff : wbOff;
        #pragma unroll
        for (int k = 0; k < DIN / 8; ++k)
            wg[k] = *(const uint4*)(WT + woff2 + (size_t)(k * DOUT + o) * 8);
    }

    for (int k = 0; k < 37; ++k) {
        int r = w * 37 + k;
        if (r >= RPB) break;
        int n = b * RPB + r;
        if (n >= N_NODES) break;

        if (lane < QP) {
            float4 sv = *(float4*)&side[r * DIN + 4 * lane];
            float4 xv = *(const float4*)(out + (size_t)n * OUT_D + cin + 4 * lane);
            __half2 A01 = __floats2half2_rn(xv.x + sv.x, xv.y + sv.y);
            __half2 A23 = __floats2half2_rn(xv.z + sv.z, xv.w + sv.w);
            __half2 B01 = __floats2half2_rn(xv.x * sv.x, xv.y * sv.y);
            __half2 B23 = __floats2half2_rn(xv.z * sv.z, xv.w * sv.w);
            ash[w][2 * lane]     = *(unsigned*)&A01;
            ash[w][2 * lane + 1] = *(unsigned*)&A23;
            bsh[w][2 * lane]     = *(unsigned*)&B01;
            bsh[w][2 * lane + 1] = *(unsigned*)&B23;
        }
        __builtin_amdgcn_wave_barrier();

        float hres = 0.f;
        if constexpr (DOUT == DIN) {
            float ag = bgc[lane], ab = bbi[lane];
            #pragma unroll
            for (int kk = 0; kk < DIN / 8; ++kk) {
                uint4 a4 = *(const uint4*)&ash[w][kk * 4];
                uint4 b4 = *(const uint4*)&bsh[w][kk * 4];
                ag = dot2(a4.x, wg[kk].x, ag); ag = dot2(a4.y, wg[kk].y, ag);
                ag = dot2(a4.z, wg[kk].z, ag); ag = dot2(a4.w, wg[kk].w, ag);
                ab = dot2(b4.x, wb[kk].x, ab); ab = dot2(b4.y, wb[kk].y, ab);
                ab = dot2(b4.z, wb[kk].z, ab); ab = dot2(b4.w, wb[kk].w, ab);
            }
            ag = ag > 0.f ? ag : 0.01f * ag;
            ab = ab > 0.f ? ab : 0.01f * ab;
            hres = ag + ab;
        } else {
            int o = lane & (DOUT - 1);
            bool gc = lane < DOUT;
            bool active = lane < 2 * DOUT;
            const unsigned* sp = gc ? &ash[w][0] : &bsh[w][0];
            float own = active ? (gc ? bgc[o] : bbi[o]) : 0.f;
            #pragma unroll
            for (int kk = 0; kk < DIN / 8; ++kk) {
                uint4 s4 = *(const uint4*)(sp + kk * 4);
                own = dot2(s4.x, wg[kk].x, own); own = dot2(s4.y, wg[kk].y, own);
                own = dot2(s4.z, wg[kk].z, own); own = dot2(s4.w, wg[kk].w, own);
            }
            own = own > 0.f ? own : 0.01f * own;
            float other = __shfl_xor(own, DOUT);
            hres = active ? own + other : 0.f;
        }

        float hq = (lane < DOUT) ? hres : 0.f;
        float ss = hq * hq;
        #pragma unroll
        for (int off = 32; off; off >>= 1) ss += __shfl_xor(ss, off);

        if (lane < DOUT) {
            float inv = 1.f / fmaxf(sqrtf(ss), 1e-12f);
            out[(size_t)n * OUT_D + cout + lane] = hres * inv;
        }
        __builtin_amdgcn_wave_barrier();
    }
}

extern "C" void kernel_launch(void* const* d_in, const int* in_sizes, int n_in,
                              void* d_out, int out_size, void* d_ws, size_t ws_size,
                              hipStream_t stream) {
    const float* ue = (const float*)d_in[0];
    const float* ee = (const float*)d_in[1];
    const float* ev = (const float*)d_in[2];
    const int*   er = (const int*)d_in[3];
    const int*   ec = (const int*)d_in[4];
    float* out = (float*)d_out;

    unsigned long long* tmp   = (unsigned long long*)d_ws;     // CSR temp
    signed char*        xq    = (signed char*)d_ws;            // after CSR
    float*              xs    = (float*)((char*)d_ws + 9600000);
    unsigned*           edges = (unsigned*)((char*)d_ws + 19200000);
    unsigned short*     rowLs = (unsigned short*)((char*)d_ws + 28800000);
    int*                table = (int*)((char*)d_ws + 33600000);
    int*                bsum  = (int*)((char*)d_ws + 34300000);
    __half*             WT    = (__half*)((char*)d_ws + 34400000);

    // ---- CSR: bucket by row/293, then col-sort within bucket ----
    histP1_kernel<<<P1_BLOCKS, 256, 0, stream>>>(er, table);
    scanA_kernel<<<SCAN_BLKS, 1024, 0, stream>>>(table, bsum, TBL);
    scanB_kernel<<<1, 1024, 0, stream>>>(bsum, SCAN_BLKS);
    scanC_kernel<<<SCAN_BLKS, 1024, 0, stream>>>(table, bsum, TBL);
    scatterP1_kernel<<<P1_BLOCKS, 256, 0, stream>>>(ev, er, ec, table, tmp);
    pass2_kernel<<<NBKT, 512, 0, stream>>>(tmp, table, edges, rowLs);

    // tmp dead; xq/xs take over
    init_x_kernel<<<(N_NODES * 16) / 256, 256, 0, stream>>>(ue, ee, out);
    wt_kernel<<<52, 256, 0, stream>>>((const float*)d_in[5],  (const float*)d_in[7],
                                      (const float*)d_in[9],  (const float*)d_in[11],
                                      (const float*)d_in[13], (const float*)d_in[15], WT);

    // layer 0: DIN=64 DOUT=64, x at col 0, write col 64
    quant_kernel<<<(N_NODES * 16) / 256, 256, 0, stream>>>(out, xq, xs, 16);
    fusedv2_kernel<64, 64><<<NBKT, 512, 0, stream>>>(table, edges, rowLs, xq, xs, out,
        WT, 0, 4096, (const float*)d_in[6], (const float*)d_in[8], 0, 64);

    // layer 1: DIN=64 DOUT=32, x at col 64, write col 128
    quant_kernel<<<(N_NODES * 16) / 256, 256, 0, stream>>>(out + 64, xq, xs, 16);
    fusedv2_kernel<64, 32><<<NBKT, 512, 0, stream>>>(table, edges, rowLs, xq, xs, out,
        WT, 8192, 10240, (const float*)d_in[10], (const float*)d_in[12], 64, 128);

    // layer 2: DIN=32 DOUT=16, x at col 128, write col 160
    quant_kernel<<<(N_NODES * 8 + 255) / 256, 256, 0, stream>>>(out + 128, xq, xs, 8);
    fusedv2_kernel<32, 16><<<NBKT, 512, 0, stream>>>(table, edges, rowLs, xq, xs, out,
        WT, 12288, 12800, (const float*)d_in[14], (const float*)d_in[16], 128, 160);
}

// Round 17
// 2242.803 us; speedup vs baseline: 1.0025x; 1.0025x over previous
//
#include <hip/hip_runtime.h>
#include <hip/hip_fp16.h>

constexpr int N_USERS = 50000;
constexpr int N_ENT   = 100000;
constexpr int N_NODES = 150000;
constexpr int N_EDGES = 2400000;
constexpr int OUT_D   = 176;               // 64 + 64 + 32 + 16

constexpr int RPB       = 293;             // rows per bucket
constexpr int NBKT      = 512;             // buckets (= fused grid, 2/CU)
constexpr int P1_BLOCKS = 293;             // pass-1 chunks
constexpr int CHUNK     = 8192;            // edges per pass-1 chunk
constexpr int TBL       = NBKT * P1_BLOCKS;            // 150016
constexpr int SCAN_BLKS = (TBL + 1023) / 1024;         // 147

// ws layout (bytes):
//   tmp u64[2.4M] @0 (19.2MB)  -- CSR temp; after CSR: xq int8[N][64] @0
//     (9.6MB) | xs float[N] @9,600,000 (0.6MB)
//   edges u32 @19,200,000 (9.6MB)   (col<<14 | val14, col-sorted per bucket)
//   rowLs u16 @28,800,000 (4.8MB)   (rowLocal per edge)
//   table int[TBL] @33,600,000 (600KB) | bsum @34,300,000 (588B)
//   WT __half[13312] @34,400,000 (26.6KB)              = ~34.43MB

typedef _Float16 h2v __attribute__((ext_vector_type(2)));
union H2U { unsigned u; h2v v; };

__device__ inline float dot2(unsigned a, unsigned b, float c) {
    H2U x, y; x.u = a; y.u = b;
    return __builtin_amdgcn_fdot2(x.v, y.v, c, false);
}

// ---------------------------------------------------------------------------
// init: out[:,0:64) = concat(ue,ee)
// ---------------------------------------------------------------------------
__global__ __launch_bounds__(256) void init_x_kernel(const float* __restrict__ ue,
                                                     const float* __restrict__ ee,
                                                     float* __restrict__ out) {
    int tid = blockIdx.x * 256 + threadIdx.x;    // N_NODES * 16 float4s
    int n = tid >> 4, q = tid & 15;
    const float* src = (n < N_USERS) ? ue + (size_t)n * 64
                                     : ee + (size_t)(n - N_USERS) * 64;
    float4 v = *(const float4*)(src + q * 4);
    *(float4*)(out + (size_t)n * OUT_D + q * 4) = v;
}

// ---------------------------------------------------------------------------
// quant: fp32 slab cols -> int8 rows (per-row max scale). din4 = DIN/4.
// ---------------------------------------------------------------------------
__global__ __launch_bounds__(256) void quant_kernel(const float* __restrict__ src,
                                                    signed char* __restrict__ xq,
                                                    float* __restrict__ xs,
                                                    int din4) {
    int tid = blockIdx.x * 256 + threadIdx.x;
    int n = tid / din4, t = tid % din4;
    if (n >= N_NODES) return;
    float4 v = *(const float4*)(src + (size_t)n * OUT_D + 4 * t);
    float m = fmaxf(fmaxf(fabsf(v.x), fabsf(v.y)), fmaxf(fabsf(v.z), fabsf(v.w)));
    for (int off = din4 >> 1; off; off >>= 1) m = fmaxf(m, __shfl_xor(m, off));
    float inv = 127.f / (m + 1e-20f);
    int q0 = __float2int_rn(v.x * inv);
    int q1 = __float2int_rn(v.y * inv);
    int q2 = __float2int_rn(v.z * inv);
    int q3 = __float2int_rn(v.w * inv);
    unsigned pk = (q0 & 0xFF) | ((q1 & 0xFF) << 8) | ((q2 & 0xFF) << 16) | ((q3 & 0xFF) << 24);
    *(unsigned*)(xq + (size_t)n * (din4 * 4) + 4 * t) = pk;
    if (t == 0) xs[n] = (m + 1e-20f) * (1.f / 127.f);
}

// ---------------------------------------------------------------------------
// Weights, fp16, k-interleaved: dest[base + (i/8)*DOUT*8 + o*8 + (i%8)]
// ---------------------------------------------------------------------------
__global__ __launch_bounds__(256) void wt_kernel(const float* __restrict__ Wg0,
                                                 const float* __restrict__ Wb0,
                                                 const float* __restrict__ Wg1,
                                                 const float* __restrict__ Wb1,
                                                 const float* __restrict__ Wg2,
                                                 const float* __restrict__ Wb2,
                                                 __half* __restrict__ WT) {
    int idx = blockIdx.x * 256 + threadIdx.x;   // 52*256 == 13312
    const float* src; int dout, base;
    if (idx < 8192)       { base = (idx < 4096) ? 0 : 4096;
                            src  = (idx < 4096) ? Wg0 : Wb0;  dout = 64; }
    else if (idx < 12288) { base = (idx < 10240) ? 8192 : 10240;
                            src  = (idx < 10240) ? Wg1 : Wb1; dout = 32; }
    else                  { base = (idx < 12800) ? 12288 : 12800;
                            src  = (idx < 12800) ? Wg2 : Wb2; dout = 16; }
    int r = idx - base;
    int i = r / dout, o = r % dout;
    int dest = base + (i / 8) * dout * 8 + o * 8 + (i % 8);
    WT[dest] = __float2half(src[r]);
}

// ---------------------------------------------------------------------------
// Pass 1: partition edges by row bucket (row / 293), 512 buckets.
// ---------------------------------------------------------------------------
__global__ __launch_bounds__(256) void histP1_kernel(const int* __restrict__ er,
                                                     int* __restrict__ table) {
    __shared__ int h[NBKT];
    for (int i = threadIdx.x; i < NBKT; i += 256) h[i] = 0;
    __syncthreads();
    int base = blockIdx.x * CHUNK;
    for (int i = threadIdx.x; i < CHUNK; i += 256) {
        int e = base + i;
        if (e < N_EDGES) atomicAdd(&h[er[e] / RPB], 1);
    }
    __syncthreads();
    for (int i = threadIdx.x; i < NBKT; i += 256)
        table[i * P1_BLOCKS + blockIdx.x] = h[i];
}

__global__ __launch_bounds__(1024) void scanA_kernel(const int* __restrict__ a,
                                                     int* __restrict__ bsum, int n) {
    __shared__ int wsum[16];
    int i = blockIdx.x * 1024 + threadIdx.x;
    int v = (i < n) ? a[i] : 0;
    #pragma unroll
    for (int off = 32; off; off >>= 1) v += __shfl_xor(v, off);
    int lane = threadIdx.x & 63, w = threadIdx.x >> 6;
    if (lane == 0) wsum[w] = v;
    __syncthreads();
    if (threadIdx.x == 0) {
        int t = 0;
        #pragma unroll
        for (int k = 0; k < 16; ++k) t += wsum[k];
        bsum[blockIdx.x] = t;
    }
}

__global__ __launch_bounds__(1024) void scanB_kernel(int* __restrict__ bsum, int n) {
    __shared__ int wtot[16];
    __shared__ int carry_s;
    int tid = threadIdx.x;
    int lane = tid & 63, w = tid >> 6;
    if (tid == 0) carry_s = 0;
    __syncthreads();
    for (int base = 0; base < n; base += 1024) {
        int i = base + tid;
        int v = (i < n) ? bsum[i] : 0;
        int incl = v;
        #pragma unroll
        for (int off = 1; off < 64; off <<= 1) {
            int t = __shfl_up(incl, off);
            if (lane >= off) incl += t;
        }
        if (lane == 63) wtot[w] = incl;
        __syncthreads();
        int woff = 0, total = 0;
        #pragma unroll
        for (int k = 0; k < 16; ++k) {
            int tk = wtot[k];
            if (k < w) woff += tk;
            total += tk;
        }
        if (i < n) bsum[i] = carry_s + woff + incl - v;
        __syncthreads();
        if (tid == 0) carry_s += total;
        __syncthreads();
    }
}

__global__ __launch_bounds__(1024) void scanC_kernel(int* __restrict__ a,
                                                     const int* __restrict__ bsum, int n) {
    __shared__ int wtot[16];
    int i = blockIdx.x * 1024 + threadIdx.x;
    int lane = threadIdx.x & 63, w = threadIdx.x >> 6;
    int v = (i < n) ? a[i] : 0;
    int incl = v;
    #pragma unroll
    for (int off = 1; off < 64; off <<= 1) {
        int t = __shfl_up(incl, off);
        if (lane >= off) incl += t;
    }
    if (lane == 63) wtot[w] = incl;
    __syncthreads();
    int woff = 0;
    #pragma unroll
    for (int k = 0; k < 16; ++k) if (k < w) woff += wtot[k];
    if (i < n) a[i] = bsum[blockIdx.x] + woff + incl - v;
}

// Pass-1 scatter: rec = rowLocal<<32 | col<<14 | val14, bucket-grouped.
__global__ __launch_bounds__(256) void scatterP1_kernel(const float* __restrict__ ev,
                                                        const int*   __restrict__ er,
                                                        const int*   __restrict__ ec,
                                                        const int*   __restrict__ table,
                                                        unsigned long long* __restrict__ tmp) {
    __shared__ int lcur[NBKT];
    for (int i = threadIdx.x; i < NBKT; i += 256)
        lcur[i] = table[i * P1_BLOCKS + blockIdx.x];
    __syncthreads();
    int base = blockIdx.x * CHUNK;
    for (int i = threadIdx.x; i < CHUNK; i += 256) {
        int e = base + i;
        if (e < N_EDGES) {
            int r = er[e], c = ec[e];
            int bkt = r / RPB;
            int rl = r - bkt * RPB;
            int v14 = (int)(ev[e] * 16384.0f + 0.5f);
            v14 = v14 > 16383 ? 16383 : v14;
            int pos = atomicAdd(&lcur[bkt], 1);
            tmp[pos] = ((unsigned long long)rl << 32)
                     | ((unsigned)c << 14) | (unsigned)v14;
        }
    }
}

// Pass 2: per bucket, sort edges by col>>9 (293 col-blocks) -> edges/rowLs.
__global__ __launch_bounds__(512) void pass2_kernel(const unsigned long long* __restrict__ tmp,
                                                    const int* __restrict__ table,
                                                    unsigned* __restrict__ edges,
                                                    unsigned short* __restrict__ rowLs) {
    __shared__ int hcnt[512];
    __shared__ int sinc[512];
    __shared__ int scur[512];
    int b = blockIdx.x;
    int tid = threadIdx.x;
    int eStart = table[b * P1_BLOCKS];
    int eEnd = (b + 1 < NBKT) ? table[(b + 1) * P1_BLOCKS] : N_EDGES;

    hcnt[tid] = 0;
    __syncthreads();
    for (int e = eStart + tid; e < eEnd; e += 512) {
        unsigned cb = ((unsigned)tmp[e]) >> 23;     // col>>9, 0..292
        atomicAdd(&hcnt[cb], 1);
    }
    __syncthreads();
    sinc[tid] = hcnt[tid];
    __syncthreads();
    #pragma unroll
    for (int off = 1; off < 512; off <<= 1) {
        int t = (tid >= off) ? sinc[tid - off] : 0;
        __syncthreads();
        sinc[tid] += t;
        __syncthreads();
    }
    scur[tid] = eStart + sinc[tid] - hcnt[tid];     // exclusive start
    __syncthreads();
    for (int e = eStart + tid; e < eEnd; e += 512) {
        unsigned long long rec = tmp[e];
        unsigned lo = (unsigned)rec;
        int pos = atomicAdd(&scur[lo >> 23], 1);
        edges[pos] = lo;
        rowLs[pos] = (unsigned short)(rec >> 32);
    }
}

// ---------------------------------------------------------------------------
// Fused layer V2: column-swept SpMM with LDS side accumulator + dense epilogue.
// Grid = 512 blocks (2/CU), block = 512 threads (8 waves).
// Each block owns 293 rows; edges sorted by column -> all concurrent blocks
// sweep xq (int8, 9.6MB) in the same order -> XCD-L2 hits by construction.
// ---------------------------------------------------------------------------
template<int DIN, int DOUT>
__global__ __launch_bounds__(512, 4) void fusedv2_kernel(
        const int*            __restrict__ table,
        const unsigned*       __restrict__ edges,
        const unsigned short* __restrict__ rowLs,
        const signed char*    __restrict__ xq,
        const float*          __restrict__ xs,
        float* __restrict__ out,
        const __half* __restrict__ WT, int wgOff, int wbOff,
        const float* __restrict__ bgc, const float* __restrict__ bbi,
        int cin, int cout) {
    __shared__ float side[RPB * DIN];
    __shared__ unsigned ash[8][DIN / 2];
    __shared__ unsigned bsh[8][DIN / 2];

    int b = blockIdx.x, tid = threadIdx.x;
    int eStart = table[b * P1_BLOCKS];
    int eEnd = (b + 1 < NBKT) ? table[(b + 1) * P1_BLOCKS] : N_EDGES;

    for (int i = tid; i < RPB * DIN; i += 512) side[i] = 0.f;
    __syncthreads();

    constexpr int QP = DIN / 4;          // lanes per edge (16 or 8)
    constexpr int EPC = 512 / QP;        // edges per chunk (32 or 64)
    int g = tid / QP;
    int t = tid % QP;
    const unsigned* xqw = (const unsigned*)xq;

    for (int e0 = eStart; e0 < eEnd; e0 += 4 * EPC) {
        unsigned rec[4]; int rl[4];
        #pragma unroll
        for (int j = 0; j < 4; ++j) {
            int idx = e0 + j * EPC + g;
            unsigned r = edges[idx];               // unguarded: ws-mapped
            unsigned short rr = rowLs[idx];        // unguarded: ws-mapped
            bool ok = idx < eEnd;
            rec[j] = ok ? r : 0u;
            rl[j]  = ok ? (int)rr : 0;
        }
        unsigned q[4]; float f[4];
        #pragma unroll
        for (int j = 0; j < 4; ++j) {
            unsigned col = rec[j] >> 14;
            q[j] = xqw[(size_t)col * QP + t];
            f[j] = (float)(rec[j] & 16383u) * (1.0f / 16384.0f) * xs[col];
        }
        #pragma unroll
        for (int j = 0; j < 4; ++j) {
            float* sp = &side[rl[j] * DIN + 4 * t];
            unsigned qq = q[j];
            atomicAdd(sp + 0, f[j] * (float)(int)(signed char)(qq & 0xFF));
            atomicAdd(sp + 1, f[j] * (float)(int)(signed char)((qq >> 8) & 0xFF));
            atomicAdd(sp + 2, f[j] * (float)(int)(signed char)((qq >> 16) & 0xFF));
            atomicAdd(sp + 3, f[j] * (float)(int)(signed char)(qq >> 24));
        }
    }
    __syncthreads();

    // ---- dense epilogue: 293 rows over 8 waves ----
    int w = tid >> 6, lane = tid & 63;

    // weights to registers once
    uint4 wg[DIN / 8], wb[DIN / 8];
    if constexpr (DOUT == DIN) {
        int o = lane;
        #pragma unroll
        for (int k = 0; k < DIN / 8; ++k) {
            wg[k] = *(const uint4*)(WT + wgOff + (size_t)(k * DOUT + o) * 8);
            wb[k] = *(const uint4*)(WT + wbOff + (size_t)(k * DOUT + o) * 8);
        }
    } else {
        int o = lane & (DOUT - 1);
        bool gc = lane < DOUT;
        int woff2 = gc ? wgOff : wbOff;
        #pragma unroll
        for (int k = 0; k < DIN / 8; ++k)
            wg[k] = *(const uint4*)(WT + woff2 + (size_t)(k * DOUT + o) * 8);
    }

    for (int k = 0; k < 37; ++k) {
        int r = w * 37 + k;
        if (r >= RPB) break;
        int n = b * RPB + r;
        if (n >= N_NODES) break;

        if (lane < QP) {
            float4 sv = *(float4*)&side[r * DIN + 4 * lane];
            float4 xv = *(const float4*)(out + (size_t)n * OUT_D + cin + 4 * lane);
            __half2 A01 = __floats2half2_rn(xv.x + sv.x, xv.y + sv.y);
            __half2 A23 = __floats2half2_rn(xv.z + sv.z, xv.w + sv.w);
            __half2 B01 = __floats2half2_rn(xv.x * sv.x, xv.y * sv.y);
            __half2 B23 = __floats2half2_rn(xv.z * sv.z, xv.w * sv.w);
            ash[w][2 * lane]     = *(unsigned*)&A01;
            ash[w][2 * lane + 1] = *(unsigned*)&A23;
            bsh[w][2 * lane]     = *(unsigned*)&B01;
            bsh[w][2 * lane + 1] = *(unsigned*)&B23;
        }
        __builtin_amdgcn_wave_barrier();

        float hres = 0.f;
        if constexpr (DOUT == DIN) {
            float ag = bgc[lane], ab = bbi[lane];
            #pragma unroll
            for (int kk = 0; kk < DIN / 8; ++kk) {
                uint4 a4 = *(const uint4*)&ash[w][kk * 4];
                uint4 b4 = *(const uint4*)&bsh[w][kk * 4];
                ag = dot2(a4.x, wg[kk].x, ag); ag = dot2(a4.y, wg[kk].y, ag);
                ag = dot2(a4.z, wg[kk].z, ag); ag = dot2(a4.w, wg[kk].w, ag);
                ab = dot2(b4.x, wb[kk].x, ab); ab = dot2(b4.y, wb[kk].y, ab);
                ab = dot2(b4.z, wb[kk].z, ab); ab = dot2(b4.w, wb[kk].w, ab);
            }
            ag = ag > 0.f ? ag : 0.01f * ag;
            ab = ab > 0.f ? ab : 0.01f * ab;
            hres = ag + ab;
        } else {
            int o = lane & (DOUT - 1);
            bool gc = lane < DOUT;
            bool active = lane < 2 * DOUT;
            const unsigned* sp = gc ? &ash[w][0] : &bsh[w][0];
            float own = active ? (gc ? bgc[o] : bbi[o]) : 0.f;
            #pragma unroll
            for (int kk = 0; kk < DIN / 8; ++kk) {
                uint4 s4 = *(const uint4*)(sp + kk * 4);
                own = dot2(s4.x, wg[kk].x, own); own = dot2(s4.y, wg[kk].y, own);
                own = dot2(s4.z, wg[kk].z, own); own = dot2(s4.w, wg[kk].w, own);
            }
            own = own > 0.f ? own : 0.01f * own;
            float other = __shfl_xor(own, DOUT);
            hres = active ? own + other : 0.f;
        }

        float hq = (lane < DOUT) ? hres : 0.f;
        float ss = hq * hq;
        #pragma unroll
        for (int off = 32; off; off >>= 1) ss += __shfl_xor(ss, off);

        if (lane < DOUT) {
            float inv = 1.f / fmaxf(sqrtf(ss), 1e-12f);
            out[(size_t)n * OUT_D + cout + lane] = hres * inv;
        }
        __builtin_amdgcn_wave_barrier();
    }
}

extern "C" void kernel_launch(void* const* d_in, const int* in_sizes, int n_in,
                              void* d_out, int out_size, void* d_ws, size_t ws_size,
                              hipStream_t stream) {
    const float* ue = (const float*)d_in[0];
    const float* ee = (const float*)d_in[1];
    const float* ev = (const float*)d_in[2];
    const int*   er = (const int*)d_in[3];
    const int*   ec = (const int*)d_in[4];
    float* out = (float*)d_out;

    unsigned long long* tmp   = (unsigned long long*)d_ws;     // CSR temp
    signed char*        xq    = (signed char*)d_ws;            // after CSR
    float*              xs    = (float*)((char*)d_ws + 9600000);
    unsigned*           edges = (unsigned*)((char*)d_ws + 19200000);
    unsigned short*     rowLs = (unsigned short*)((char*)d_ws + 28800000);
    int*                table = (int*)((char*)d_ws + 33600000);
    int*                bsum  = (int*)((char*)d_ws + 34300000);
    __half*             WT    = (__half*)((char*)d_ws + 34400000);

    // ---- CSR: bucket by row/293, then col-sort within bucket ----
    histP1_kernel<<<P1_BLOCKS, 256, 0, stream>>>(er, table);
    scanA_kernel<<<SCAN_BLKS, 1024, 0, stream>>>(table, bsum, TBL);
    scanB_kernel<<<1, 1024, 0, stream>>>(bsum, SCAN_BLKS);
    scanC_kernel<<<SCAN_BLKS, 1024, 0, stream>>>(table, bsum, TBL);
    scatterP1_kernel<<<P1_BLOCKS, 256, 0, stream>>>(ev, er, ec, table, tmp);
    pass2_kernel<<<NBKT, 512, 0, stream>>>(tmp, table, edges, rowLs);

    // tmp dead; xq/xs take over
    init_x_kernel<<<(N_NODES * 16) / 256, 256, 0, stream>>>(ue, ee, out);
    wt_kernel<<<52, 256, 0, stream>>>((const float*)d_in[5],  (const float*)d_in[7],
                                      (const float*)d_in[9],  (const float*)d_in[11],
                                      (const float*)d_in[13], (const float*)d_in[15], WT);

    // layer 0: DIN=64 DOUT=64, x at col 0, write col 64
    quant_kernel<<<(N_NODES * 16) / 256, 256, 0, stream>>>(out, xq, xs, 16);
    fusedv2_kernel<64, 64><<<NBKT, 512, 0, stream>>>(table, edges, rowLs, xq, xs, out,
        WT, 0, 4096, (const float*)d_in[6], (const float*)d_in[8], 0, 64);

    // layer 1: DIN=64 DOUT=32, x at col 64, write col 128
    quant_kernel<<<(N_NODES * 16) / 256, 256, 0, stream>>>(out + 64, xq, xs, 16);
    fusedv2_kernel<64, 32><<<NBKT, 512, 0, stream>>>(table, edges, rowLs, xq, xs, out,
        WT, 8192, 10240, (const float*)d_in[10], (const float*)d_in[12], 64, 128);

    // layer 2: DIN=32 DOUT=16, x at col 128, write col 160
    quant_kernel<<<(N_NODES * 8 + 255) / 256, 256, 0, stream>>>(out + 128, xq, xs, 8);
    fusedv2_kernel<32, 16><<<NBKT, 512, 0, stream>>>(table, edges, rowLs, xq, xs, out,
        WT, 12288, 12800, (const float*)d_in[14], (const float*)d_in[16], 128, 160);
}

// Round 19
// 417.489 us; speedup vs baseline: 5.3854x; 5.3721x over previous
//
#include <hip/hip_runtime.h>
#include <hip/hip_fp16.h>

constexpr int N_USERS = 50000;
constexpr int N_ENT   = 100000;
constexpr int N_NODES = 150000;
constexpr int N_EDGES = 2400000;
constexpr int OUT_D   = 176;               // 64 + 64 + 32 + 16

constexpr int NBKT      = 293;             // coarse buckets = row >> 9
constexpr int P1_BLOCKS = 293;             // pass-1 blocks
constexpr int CHUNK     = 8192;            // edges per pass-1 block
constexpr int TBL       = NBKT * P1_BLOCKS;            // 85849
constexpr int SCAN_BLKS = (TBL + 1023) / 1024;         // 84

// ws layout (bytes):
//   tmp u64[2.4M] @0 (19.2MB)  -- CSR temp; later xh fp16 [N][64] @0
//   edges u32 @19,200,000 (9.6MB)
//   cursor int[N] @28,800,000 (0.6MB)
//   table int[TBL] @29,400,000 (343KB) | bsum @30,000,000 (336B)
//   WT __half[13312] @30,100,000 (26.6KB)              = ~30.13MB

typedef _Float16 h2v __attribute__((ext_vector_type(2)));
typedef float    f2v __attribute__((ext_vector_type(2)));   // NT-load-able
union H2U { unsigned u; h2v v; };

__device__ inline float dot2(unsigned a, unsigned b, float c) {
    H2U x, y; x.u = a; y.u = b;
    return __builtin_amdgcn_fdot2(x.v, y.v, c, false);
}

// ---------------------------------------------------------------------------
// init: out[:,0:64) = concat(ue,ee);  xh = fp16 shadow [N][64]
// ---------------------------------------------------------------------------
__global__ __launch_bounds__(256) void init_x_kernel(const float* __restrict__ ue,
                                                     const float* __restrict__ ee,
                                                     float* __restrict__ out,
                                                     __half* __restrict__ xh) {
    int tid = blockIdx.x * 256 + threadIdx.x;    // N_NODES * 16 float4s
    int n = tid >> 4, q = tid & 15;
    const float* src = (n < N_USERS) ? ue + (size_t)n * 64
                                     : ee + (size_t)(n - N_USERS) * 64;
    float4 v = *(const float4*)(src + q * 4);
    *(float4*)(out + (size_t)n * OUT_D + q * 4) = v;
    union { __half2 h[2]; uint2 u; } pk;
    pk.h[0] = __floats2half2_rn(v.x, v.y);
    pk.h[1] = __floats2half2_rn(v.z, v.w);
    *(uint2*)(xh + (size_t)n * 64 + q * 4) = pk.u;
}

// fp32 slab column block -> dense fp16 shadow ([N][DIN]); 2 dims per thread.
// out-read is a one-use stream: nontemporal. xh store normal (next gather set).
__global__ __launch_bounds__(256) void conv_kernel(const float* __restrict__ src,
                                                   __half* __restrict__ xh, int DIN) {
    int tid = blockIdx.x * 256 + threadIdx.x;    // N_NODES * DIN/2
    int n = tid / (DIN / 2), t = tid % (DIN / 2);
    f2v v = __builtin_nontemporal_load((const f2v*)(src + (size_t)n * OUT_D + 2 * t));
    *(__half2*)(xh + (size_t)n * DIN + 2 * t) = __floats2half2_rn(v.x, v.y);
}

// ---------------------------------------------------------------------------
// Weights, fp16, k-interleaved for coalesced per-o uint4 reads:
//   dest[base + (i/8)*DOUT*8 + o*8 + (i%8)] = W[i*DOUT + o]
// ---------------------------------------------------------------------------
__global__ __launch_bounds__(256) void wt_kernel(const float* __restrict__ Wg0,
                                                 const float* __restrict__ Wb0,
                                                 const float* __restrict__ Wg1,
                                                 const float* __restrict__ Wb1,
                                                 const float* __restrict__ Wg2,
                                                 const float* __restrict__ Wb2,
                                                 __half* __restrict__ WT) {
    int idx = blockIdx.x * 256 + threadIdx.x;   // 52*256 == 13312
    const float* src; int dout, base;
    if (idx < 8192)       { base = (idx < 4096) ? 0 : 4096;
                            src  = (idx < 4096) ? Wg0 : Wb0;  dout = 64; }
    else if (idx < 12288) { base = (idx < 10240) ? 8192 : 10240;
                            src  = (idx < 10240) ? Wg1 : Wb1; dout = 32; }
    else                  { base = (idx < 12800) ? 12288 : 12800;
                            src  = (idx < 12800) ? Wg2 : Wb2; dout = 16; }
    int r = idx - base;
    int i = r / dout, o = r % dout;
    int dest = base + (i / 8) * dout * 8 + o * 8 + (i % 8);
    WT[dest] = __float2half(src[r]);
}

// ---------------------------------------------------------------------------
// Two-level bucket sort. Pass 1: partition by coarse bucket (row>>9).
// ---------------------------------------------------------------------------
__global__ __launch_bounds__(256) void histP1_kernel(const int* __restrict__ er,
                                                     int* __restrict__ table) {
    __shared__ int h[NBKT];
    for (int i = threadIdx.x; i < NBKT; i += 256) h[i] = 0;
    __syncthreads();
    int base = blockIdx.x * CHUNK;
    for (int i = threadIdx.x; i < CHUNK; i += 256) {
        int e = base + i;
        if (e < N_EDGES) atomicAdd(&h[er[e] >> 9], 1);
    }
    __syncthreads();
    for (int i = threadIdx.x; i < NBKT; i += 256)
        table[i * P1_BLOCKS + blockIdx.x] = h[i];
}

__global__ __launch_bounds__(1024) void scanA_kernel(const int* __restrict__ a,
                                                     int* __restrict__ bsum, int n) {
    __shared__ int wsum[16];
    int i = blockIdx.x * 1024 + threadIdx.x;
    int v = (i < n) ? a[i] : 0;
    #pragma unroll
    for (int off = 32; off; off >>= 1) v += __shfl_xor(v, off);
    int lane = threadIdx.x & 63, w = threadIdx.x >> 6;
    if (lane == 0) wsum[w] = v;
    __syncthreads();
    if (threadIdx.x == 0) {
        int t = 0;
        #pragma unroll
        for (int k = 0; k < 16; ++k) t += wsum[k];
        bsum[blockIdx.x] = t;
    }
}

__global__ __launch_bounds__(1024) void scanB_kernel(int* __restrict__ bsum, int n) {
    __shared__ int wtot[16];
    __shared__ int carry_s;
    int tid = threadIdx.x;
    int lane = tid & 63, w = tid >> 6;
    if (tid == 0) carry_s = 0;
    __syncthreads();
    for (int base = 0; base < n; base += 1024) {
        int i = base + tid;
        int v = (i < n) ? bsum[i] : 0;
        int incl = v;
        #pragma unroll
        for (int off = 1; off < 64; off <<= 1) {
            int t = __shfl_up(incl, off);
            if (lane >= off) incl += t;
        }
        if (lane == 63) wtot[w] = incl;
        __syncthreads();
        int woff = 0, total = 0;
        #pragma unroll
        for (int k = 0; k < 16; ++k) {
            int tk = wtot[k];
            if (k < w) woff += tk;
            total += tk;
        }
        if (i < n) bsum[i] = carry_s + woff + incl - v;
        __syncthreads();
        if (tid == 0) carry_s += total;
        __syncthreads();
    }
}

__global__ __launch_bounds__(1024) void scanC_kernel(int* __restrict__ a,
                                                     const int* __restrict__ bsum, int n) {
    __shared__ int wtot[16];
    int i = blockIdx.x * 1024 + threadIdx.x;
    int lane = threadIdx.x & 63, w = threadIdx.x >> 6;
    int v = (i < n) ? a[i] : 0;
    int incl = v;
    #pragma unroll
    for (int off = 1; off < 64; off <<= 1) {
        int t = __shfl_up(incl, off);
        if (lane >= off) incl += t;
    }
    if (lane == 63) wtot[w] = incl;
    __syncthreads();
    int woff = 0;
    #pragma unroll
    for (int k = 0; k < 16; ++k) if (k < w) woff += wtot[k];
    if (i < n) a[i] = bsum[blockIdx.x] + woff + incl - v;
}

// Pass-1 scatter: rec = (row&511)<<32 | col<<14 | val14
__global__ __launch_bounds__(256) void scatterP1_kernel(const float* __restrict__ ev,
                                                        const int*   __restrict__ er,
                                                        const int*   __restrict__ ec,
                                                        const int*   __restrict__ table,
                                                        unsigned long long* __restrict__ tmp) {
    __shared__ int lcur[NBKT];
    for (int i = threadIdx.x; i < NBKT; i += 256)
        lcur[i] = table[i * P1_BLOCKS + blockIdx.x];
    __syncthreads();
    int base = blockIdx.x * CHUNK;
    for (int i = threadIdx.x; i < CHUNK; i += 256) {
        int e = base + i;
        if (e < N_EDGES) {
            int r = er[e], c = ec[e];
            int v14 = (int)(ev[e] * 16384.0f + 0.5f);
            v14 = v14 > 16383 ? 16383 : v14;
            int pos = atomicAdd(&lcur[r >> 9], 1);
            tmp[pos] = ((unsigned long long)(r & 511) << 32)
                     | ((unsigned)c << 14) | (unsigned)v14;
        }
    }
}

// Pass 2: per bucket: LDS hist -> LDS scan -> cursor[] + dense scatter.
__global__ __launch_bounds__(512) void pass2_kernel(const unsigned long long* __restrict__ tmp,
                                                    const int* __restrict__ table,
                                                    unsigned* __restrict__ edges,
                                                    int* __restrict__ cursor) {
    __shared__ int hcnt[512];
    __shared__ int sinc[512];
    __shared__ int lcur[512];
    int b = blockIdx.x;
    int tid = threadIdx.x;
    int eStart = table[b * P1_BLOCKS];
    int eEnd = (b + 1 < NBKT) ? table[(b + 1) * P1_BLOCKS] : N_EDGES;

    hcnt[tid] = 0;
    __syncthreads();
    for (int e = eStart + tid; e < eEnd; e += 512)
        atomicAdd(&hcnt[(int)(tmp[e] >> 32)], 1);
    __syncthreads();
    sinc[tid] = hcnt[tid];
    __syncthreads();
    #pragma unroll
    for (int off = 1; off < 512; off <<= 1) {
        int t = (tid >= off) ? sinc[tid - off] : 0;
        __syncthreads();
        sinc[tid] += t;
        __syncthreads();
    }
    int row = b * 512 + tid;
    if (row < N_NODES) cursor[row] = eStart + sinc[tid];   // inclusive end
    lcur[tid] = eStart + sinc[tid] - hcnt[tid];            // start
    __syncthreads();
    for (int e = eStart + tid; e < eEnd; e += 512) {
        unsigned long long rec = tmp[e];
        int pos = atomicAdd(&lcur[(int)(rec >> 32)], 1);
        edges[pos] = (unsigned)rec;
    }
}

// ---------------------------------------------------------------------------
// Fused layer (R9 structure + nontemporal stream hints). One wave per node.
// Gather: 8 independent predicated edge loads (NT) + 8 row-gathers in flight
// (gathers are the ONLY retained lines). x-row read NT, output store NT.
// Dense: k-interleaved fp16 weights in registers + dot2.
// ---------------------------------------------------------------------------
template<int DIN, int DOUT>
__global__ __launch_bounds__(256, 4) void fused_layer_kernel(
        const int*          __restrict__ cursor,
        const unsigned int* __restrict__ edges,
        const __half*       __restrict__ xh,
        float* __restrict__ out,
        const __half* __restrict__ WT, int wgOff, int wbOff,
        const float* __restrict__ bgc, const float* __restrict__ bbi,
        int cin, int cout) {
    __shared__ unsigned ash[4][DIN / 2];
    __shared__ unsigned bsh[4][DIN / 2];

    int tid = threadIdx.x;
    int w = tid >> 6, lane = tid & 63;
    int n = blockIdx.x * 4 + w;

    constexpr int HP = DIN / 2;         // half2 per row
    constexpr int NE = 128 / DIN;       // edges per wave-gather (2 or 4)
    int g = lane / HP;                  // edge slot within gather instr
    int t = lane % HP;                  // dim-pair index

    int s = n ? cursor[n - 1] : 0;
    int e_end = cursor[n];

    // hoist x read (one-use stream: nontemporal; overlaps with gather latency)
    f2v xv = {0.f, 0.f};
    if (lane < HP)
        xv = __builtin_nontemporal_load(
                 (const f2v*)(out + (size_t)n * OUT_D + cin + 2 * lane));

    const __half2* xr = (const __half2*)xh;
    float accx = 0.f, accy = 0.f;

    for (int e = s; e < e_end; e += 8 * NE) {
        unsigned ue[8];
        #pragma unroll
        for (int j = 0; j < 8; ++j) {
            int i = e + j * NE + g;
            // edge stream: one-use, nontemporal (don't evict gather lines).
            // unguarded load lands in ws (cursor area) then select.
            unsigned raw = __builtin_nontemporal_load(edges + i);
            ue[j] = (i < e_end) ? raw : 0u;
        }
        float vv[8]; float2 f[8];
        #pragma unroll
        for (int j = 0; j < 8; ++j) {
            unsigned c = ue[j] >> 14;
            vv[j] = (float)(ue[j] & 16383u) * (1.0f / 16384.0f);
            f[j] = __half22float2(xr[(size_t)c * HP + t]);   // retained in L2
        }
        #pragma unroll
        for (int j = 0; j < 8; ++j) {
            accx += vv[j] * f[j].x;
            accy += vv[j] * f[j].y;
        }
    }
    // fold edge slots down to lanes 0..HP-1
    #pragma unroll
    for (int m = 32; m >= HP; m >>= 1) {
        accx += __shfl_xor(accx, m);
        accy += __shfl_xor(accy, m);
    }

    if (lane < HP) {
        __half2 a2 = __floats2half2_rn(xv.x + accx, xv.y + accy);
        __half2 b2 = __floats2half2_rn(xv.x * accx, xv.y * accy);
        ash[w][lane] = *(unsigned*)&a2;
        bsh[w][lane] = *(unsigned*)&b2;
    }
    __syncthreads();

    float hres = 0.f;
    if constexpr (DOUT == DIN) {
        int o = lane;
        uint4 wg[DIN / 8], wb[DIN / 8];
        #pragma unroll
        for (int k = 0; k < DIN / 8; ++k) {
            wg[k] = *(const uint4*)(WT + wgOff + (size_t)(k * DOUT + o) * 8);
            wb[k] = *(const uint4*)(WT + wbOff + (size_t)(k * DOUT + o) * 8);
        }
        float ag = bgc[o], ab = bbi[o];
        #pragma unroll
        for (int k = 0; k < DIN / 8; ++k) {
            uint4 a4 = *(const uint4*)&ash[w][k * 4];
            uint4 b4 = *(const uint4*)&bsh[w][k * 4];
            ag = dot2(a4.x, wg[k].x, ag); ag = dot2(a4.y, wg[k].y, ag);
            ag = dot2(a4.z, wg[k].z, ag); ag = dot2(a4.w, wg[k].w, ag);
            ab = dot2(b4.x, wb[k].x, ab); ab = dot2(b4.y, wb[k].y, ab);
            ab = dot2(b4.z, wb[k].z, ab); ab = dot2(b4.w, wb[k].w, ab);
        }
        ag = ag > 0.f ? ag : 0.01f * ag;
        ab = ab > 0.f ? ab : 0.01f * ab;
        hres = ag + ab;
    } else {
        int o = lane & (DOUT - 1);
        bool gc = lane < DOUT;
        bool active = lane < 2 * DOUT;
        int woff2 = gc ? wgOff : wbOff;
        uint4 wr[DIN / 8];
        #pragma unroll
        for (int k = 0; k < DIN / 8; ++k)
            wr[k] = *(const uint4*)(WT + woff2 + (size_t)(k * DOUT + o) * 8);
        const unsigned* sp = gc ? &ash[w][0] : &bsh[w][0];
        float own = active ? (gc ? bgc[o] : bbi[o]) : 0.f;
        #pragma unroll
        for (int k = 0; k < DIN / 8; ++k) {
            uint4 s4 = *(const uint4*)(sp + k * 4);
            own = dot2(s4.x, wr[k].x, own); own = dot2(s4.y, wr[k].y, own);
            own = dot2(s4.z, wr[k].z, own); own = dot2(s4.w, wr[k].w, own);
        }
        own = own > 0.f ? own : 0.01f * own;
        float other = __shfl_xor(own, DOUT);
        hres = own + other;
    }

    float hq = (lane < DOUT) ? hres : 0.f;
    float ss = hq * hq;
    #pragma unroll
    for (int off = 32; off; off >>= 1) ss += __shfl_xor(ss, off);

    if (lane < DOUT) {
        float inv = 1.f / fmaxf(sqrtf(ss), 1e-12f);
        __builtin_nontemporal_store(hres * inv,
                                    out + (size_t)n * OUT_D + cout + lane);
    }
}

extern "C" void kernel_launch(void* const* d_in, const int* in_sizes, int n_in,
                              void* d_out, int out_size, void* d_ws, size_t ws_size,
                              hipStream_t stream) {
    const float* ue = (const float*)d_in[0];
    const float* ee = (const float*)d_in[1];
    const float* ev = (const float*)d_in[2];
    const int*   er = (const int*)d_in[3];
    const int*   ec = (const int*)d_in[4];
    float* out = (float*)d_out;

    unsigned long long* tmp    = (unsigned long long*)d_ws;     // CSR temp
    __half*             xh     = (__half*)d_ws;                 // after CSR
    unsigned int*       edges  = (unsigned int*)((char*)d_ws + 19200000);
    int*                cursor = (int*)((char*)d_ws + 28800000);
    int*                table  = (int*)((char*)d_ws + 29400000);
    int*                bsum   = (int*)((char*)d_ws + 30000000);
    __half*             WT     = (__half*)((char*)d_ws + 30100000);

    // ---- CSR via two-level bucket sort ----
    histP1_kernel<<<P1_BLOCKS, 256, 0, stream>>>(er, table);
    scanA_kernel<<<SCAN_BLKS, 1024, 0, stream>>>(table, bsum, TBL);
    scanB_kernel<<<1, 1024, 0, stream>>>(bsum, SCAN_BLKS);
    scanC_kernel<<<SCAN_BLKS, 1024, 0, stream>>>(table, bsum, TBL);
    scatterP1_kernel<<<P1_BLOCKS, 256, 0, stream>>>(ev, er, ec, table, tmp);
    pass2_kernel<<<NBKT, 512, 0, stream>>>(tmp, table, edges, cursor);

    // tmp dead; xh takes over the region
    init_x_kernel<<<(N_NODES * 16) / 256, 256, 0, stream>>>(ue, ee, out, xh);
    wt_kernel<<<52, 256, 0, stream>>>((const float*)d_in[5],  (const float*)d_in[7],
                                      (const float*)d_in[9],  (const float*)d_in[11],
                                      (const float*)d_in[13], (const float*)d_in[15], WT);

    const int GRID = N_NODES / 4;   // 37500

    // layer 0: DIN=64 DOUT=64, x at col 0, write col 64
    fused_layer_kernel<64, 64><<<GRID, 256, 0, stream>>>(cursor, edges, xh, out,
        WT, 0, 4096, (const float*)d_in[6], (const float*)d_in[8], 0, 64);
    conv_kernel<<<(N_NODES * 32) / 256, 256, 0, stream>>>(out + 64, xh, 64);

    // layer 1: DIN=64 DOUT=32, x at col 64, write col 128
    fused_layer_kernel<64, 32><<<GRID, 256, 0, stream>>>(cursor, edges, xh, out,
        WT, 8192, 10240, (const float*)d_in[10], (const float*)d_in[12], 64, 128);
    conv_kernel<<<(N_NODES * 16) / 256, 256, 0, stream>>>(out + 128, xh, 32);

    // layer 2: DIN=32 DOUT=16, x at col 128, write col 160
    fused_layer_kernel<32, 16><<<GRID, 256, 0, stream>>>(cursor, edges, xh, out,
        WT, 12288, 12800, (const float*)d_in[14], (const float*)d_in[16], 128, 160);
}

// Round 20
// 374.535 us; speedup vs baseline: 6.0030x; 1.1147x over previous
//
#include <hip/hip_runtime.h>
#include <hip/hip_fp16.h>

constexpr int N_USERS = 50000;
constexpr int N_ENT   = 100000;
constexpr int N_NODES = 150000;
constexpr int N_EDGES = 2400000;
constexpr int OUT_D   = 176;               // 64 + 64 + 32 + 16

constexpr int NBKT      = 293;             // coarse buckets = row >> 9
constexpr int P1_BLOCKS = 293;             // pass-1 blocks
constexpr int CHUNK     = 8192;            // edges per pass-1 block
constexpr int TBL       = NBKT * P1_BLOCKS;            // 85849
constexpr int SCAN_BLKS = (TBL + 1023) / 1024;         // 84

// ws layout (bytes):
//   tmp u64[2.4M] @0 (19.2MB)  -- CSR temp; later xh fp16 [N][64] @0
//   edges u32 @19,200,000 (9.6MB)
//   cursor int[N] @28,800,000 (0.6MB)
//   table int[TBL] @29,400,000 (343KB) | bsum @30,000,000 (336B)
//   WT __half[13312] @30,100,000 (26.6KB)              = ~30.13MB

typedef _Float16 h2v __attribute__((ext_vector_type(2)));
union H2U { unsigned u; h2v v; };

__device__ inline float dot2(unsigned a, unsigned b, float c) {
    H2U x, y; x.u = a; y.u = b;
    return __builtin_amdgcn_fdot2(x.v, y.v, c, false);
}

// ---------------------------------------------------------------------------
// init: out[:,0:64) = concat(ue,ee);  xh = fp16 shadow [N][64]
// ---------------------------------------------------------------------------
__global__ __launch_bounds__(256) void init_x_kernel(const float* __restrict__ ue,
                                                     const float* __restrict__ ee,
                                                     float* __restrict__ out,
                                                     __half* __restrict__ xh) {
    int tid = blockIdx.x * 256 + threadIdx.x;    // N_NODES * 16 float4s
    int n = tid >> 4, q = tid & 15;
    const float* src = (n < N_USERS) ? ue + (size_t)n * 64
                                     : ee + (size_t)(n - N_USERS) * 64;
    float4 v = *(const float4*)(src + q * 4);
    *(float4*)(out + (size_t)n * OUT_D + q * 4) = v;
    union { __half2 h[2]; uint2 u; } pk;
    pk.h[0] = __floats2half2_rn(v.x, v.y);
    pk.h[1] = __floats2half2_rn(v.z, v.w);
    *(uint2*)(xh + (size_t)n * 64 + q * 4) = pk.u;
}

// fp32 slab column block -> dense fp16 shadow ([N][DIN]); 2 dims per thread
__global__ __launch_bounds__(256) void conv_kernel(const float* __restrict__ src,
                                                   __half* __restrict__ xh, int DIN) {
    int tid = blockIdx.x * 256 + threadIdx.x;    // N_NODES * DIN/2
    int n = tid / (DIN / 2), t = tid % (DIN / 2);
    float2 v = *(const float2*)(src + (size_t)n * OUT_D + 2 * t);
    *(__half2*)(xh + (size_t)n * DIN + 2 * t) = __floats2half2_rn(v.x, v.y);
}

// ---------------------------------------------------------------------------
// Weights, fp16, k-interleaved for coalesced per-o uint4 reads:
//   dest[base + (i/8)*DOUT*8 + o*8 + (i%8)] = W[i*DOUT + o]
// ---------------------------------------------------------------------------
__global__ __launch_bounds__(256) void wt_kernel(const float* __restrict__ Wg0,
                                                 const float* __restrict__ Wb0,
                                                 const float* __restrict__ Wg1,
                                                 const float* __restrict__ Wb1,
                                                 const float* __restrict__ Wg2,
                                                 const float* __restrict__ Wb2,
                                                 __half* __restrict__ WT) {
    int idx = blockIdx.x * 256 + threadIdx.x;   // 52*256 == 13312
    const float* src; int dout, base;
    if (idx < 8192)       { base = (idx < 4096) ? 0 : 4096;
                            src  = (idx < 4096) ? Wg0 : Wb0;  dout = 64; }
    else if (idx < 12288) { base = (idx < 10240) ? 8192 : 10240;
                            src  = (idx < 10240) ? Wg1 : Wb1; dout = 32; }
    else                  { base = (idx < 12800) ? 12288 : 12800;
                            src  = (idx < 12800) ? Wg2 : Wb2; dout = 16; }
    int r = idx - base;
    int i = r / dout, o = r % dout;
    int dest = base + (i / 8) * dout * 8 + o * 8 + (i % 8);
    WT[dest] = __float2half(src[r]);
}

// ---------------------------------------------------------------------------
// Two-level bucket sort. Pass 1: partition by coarse bucket (row>>9).
// ---------------------------------------------------------------------------
__global__ __launch_bounds__(256) void histP1_kernel(const int* __restrict__ er,
                                                     int* __restrict__ table) {
    __shared__ int h[NBKT];
    for (int i = threadIdx.x; i < NBKT; i += 256) h[i] = 0;
    __syncthreads();
    int base = blockIdx.x * CHUNK;
    for (int i = threadIdx.x; i < CHUNK; i += 256) {
        int e = base + i;
        if (e < N_EDGES) atomicAdd(&h[er[e] >> 9], 1);
    }
    __syncthreads();
    for (int i = threadIdx.x; i < NBKT; i += 256)
        table[i * P1_BLOCKS + blockIdx.x] = h[i];
}

__global__ __launch_bounds__(1024) void scanA_kernel(const int* __restrict__ a,
                                                     int* __restrict__ bsum, int n) {
    __shared__ int wsum[16];
    int i = blockIdx.x * 1024 + threadIdx.x;
    int v = (i < n) ? a[i] : 0;
    #pragma unroll
    for (int off = 32; off; off >>= 1) v += __shfl_xor(v, off);
    int lane = threadIdx.x & 63, w = threadIdx.x >> 6;
    if (lane == 0) wsum[w] = v;
    __syncthreads();
    if (threadIdx.x == 0) {
        int t = 0;
        #pragma unroll
        for (int k = 0; k < 16; ++k) t += wsum[k];
        bsum[blockIdx.x] = t;
    }
}

__global__ __launch_bounds__(1024) void scanB_kernel(int* __restrict__ bsum, int n) {
    __shared__ int wtot[16];
    __shared__ int carry_s;
    int tid = threadIdx.x;
    int lane = tid & 63, w = tid >> 6;
    if (tid == 0) carry_s = 0;
    __syncthreads();
    for (int base = 0; base < n; base += 1024) {
        int i = base + tid;
        int v = (i < n) ? bsum[i] : 0;
        int incl = v;
        #pragma unroll
        for (int off = 1; off < 64; off <<= 1) {
            int t = __shfl_up(incl, off);
            if (lane >= off) incl += t;
        }
        if (lane == 63) wtot[w] = incl;
        __syncthreads();
        int woff = 0, total = 0;
        #pragma unroll
        for (int k = 0; k < 16; ++k) {
            int tk = wtot[k];
            if (k < w) woff += tk;
            total += tk;
        }
        if (i < n) bsum[i] = carry_s + woff + incl - v;
        __syncthreads();
        if (tid == 0) carry_s += total;
        __syncthreads();
    }
}

__global__ __launch_bounds__(1024) void scanC_kernel(int* __restrict__ a,
                                                     const int* __restrict__ bsum, int n) {
    __shared__ int wtot[16];
    int i = blockIdx.x * 1024 + threadIdx.x;
    int lane = threadIdx.x & 63, w = threadIdx.x >> 6;
    int v = (i < n) ? a[i] : 0;
    int incl = v;
    #pragma unroll
    for (int off = 1; off < 64; off <<= 1) {
        int t = __shfl_up(incl, off);
        if (lane >= off) incl += t;
    }
    if (lane == 63) wtot[w] = incl;
    __syncthreads();
    int woff = 0;
    #pragma unroll
    for (int k = 0; k < 16; ++k) if (k < w) woff += wtot[k];
    if (i < n) a[i] = bsum[blockIdx.x] + woff + incl - v;
}

// Pass-1 scatter: rec = (row&511)<<32 | col<<14 | val14
__global__ __launch_bounds__(256) void scatterP1_kernel(const float* __restrict__ ev,
                                                        const int*   __restrict__ er,
                                                        const int*   __restrict__ ec,
                                                        const int*   __restrict__ table,
                                                        unsigned long long* __restrict__ tmp) {
    __shared__ int lcur[NBKT];
    for (int i = threadIdx.x; i < NBKT; i += 256)
        lcur[i] = table[i * P1_BLOCKS + blockIdx.x];
    __syncthreads();
    int base = blockIdx.x * CHUNK;
    for (int i = threadIdx.x; i < CHUNK; i += 256) {
        int e = base + i;
        if (e < N_EDGES) {
            int r = er[e], c = ec[e];
            int v14 = (int)(ev[e] * 16384.0f + 0.5f);
            v14 = v14 > 16383 ? 16383 : v14;
            int pos = atomicAdd(&lcur[r >> 9], 1);
            tmp[pos] = ((unsigned long long)(r & 511) << 32)
                     | ((unsigned)c << 14) | (unsigned)v14;
        }
    }
}

// Pass 2: per bucket: LDS hist -> LDS scan -> cursor[] + dense scatter.
__global__ __launch_bounds__(512) void pass2_kernel(const unsigned long long* __restrict__ tmp,
                                                    const int* __restrict__ table,
                                                    unsigned* __restrict__ edges,
                                                    int* __restrict__ cursor) {
    __shared__ int hcnt[512];
    __shared__ int sinc[512];
    __shared__ int lcur[512];
    int b = blockIdx.x;
    int tid = threadIdx.x;
    int eStart = table[b * P1_BLOCKS];
    int eEnd = (b + 1 < NBKT) ? table[(b + 1) * P1_BLOCKS] : N_EDGES;

    hcnt[tid] = 0;
    __syncthreads();
    for (int e = eStart + tid; e < eEnd; e += 512)
        atomicAdd(&hcnt[(int)(tmp[e] >> 32)], 1);
    __syncthreads();
    sinc[tid] = hcnt[tid];
    __syncthreads();
    #pragma unroll
    for (int off = 1; off < 512; off <<= 1) {
        int t = (tid >= off) ? sinc[tid - off] : 0;
        __syncthreads();
        sinc[tid] += t;
        __syncthreads();
    }
    int row = b * 512 + tid;
    if (row < N_NODES) cursor[row] = eStart + sinc[tid];   // inclusive end
    lcur[tid] = eStart + sinc[tid] - hcnt[tid];            // start
    __syncthreads();
    for (int e = eStart + tid; e < eEnd; e += 512) {
        unsigned long long rec = tmp[e];
        int pos = atomicAdd(&lcur[(int)(rec >> 32)], 1);
        edges[pos] = (unsigned)rec;
    }
}

// ---------------------------------------------------------------------------
// Fused layer (R9 proven-best). One wave per node.
// Gather: 8 independent predicated edge loads + 8 row-gathers in flight.
// Dense: k-interleaved fp16 weights in registers + dot2.
// ---------------------------------------------------------------------------
template<int DIN, int DOUT>
__global__ __launch_bounds__(256, 4) void fused_layer_kernel(
        const int*          __restrict__ cursor,
        const unsigned int* __restrict__ edges,
        const __half*       __restrict__ xh,
        float* __restrict__ out,
        const __half* __restrict__ WT, int wgOff, int wbOff,
        const float* __restrict__ bgc, const float* __restrict__ bbi,
        int cin, int cout) {
    __shared__ unsigned ash[4][DIN / 2];
    __shared__ unsigned bsh[4][DIN / 2];

    int tid = threadIdx.x;
    int w = tid >> 6, lane = tid & 63;
    int n = blockIdx.x * 4 + w;

    constexpr int HP = DIN / 2;         // half2 per row
    constexpr int NE = 128 / DIN;       // edges per wave-gather (2 or 4)
    int g = lane / HP;                  // edge slot within gather instr
    int t = lane % HP;                  // dim-pair index

    int s = n ? cursor[n - 1] : 0;
    int e_end = cursor[n];

    // hoist x read (overlaps with gather latency)
    float2 xv = make_float2(0.f, 0.f);
    if (lane < HP) xv = *(const float2*)(out + (size_t)n * OUT_D + cin + 2 * lane);

    const __half2* xr = (const __half2*)xh;
    float accx = 0.f, accy = 0.f;

    for (int e = s; e < e_end; e += 8 * NE) {
        unsigned ue[8];
        #pragma unroll
        for (int j = 0; j < 8; ++j) {
            int i = e + j * NE + g;
            unsigned raw = edges[i];     // unguarded: lands in ws (cursor area)
            ue[j] = (i < e_end) ? raw : 0u;
        }
        float vv[8]; float2 f[8];
        #pragma unroll
        for (int j = 0; j < 8; ++j) {
            unsigned c = ue[j] >> 14;
            vv[j] = (float)(ue[j] & 16383u) * (1.0f / 16384.0f);
            f[j] = __half22float2(xr[(size_t)c * HP + t]);
        }
        #pragma unroll
        for (int j = 0; j < 8; ++j) {
            accx += vv[j] * f[j].x;
            accy += vv[j] * f[j].y;
        }
    }
    // fold edge slots down to lanes 0..HP-1
    #pragma unroll
    for (int m = 32; m >= HP; m >>= 1) {
        accx += __shfl_xor(accx, m);
        accy += __shfl_xor(accy, m);
    }

    if (lane < HP) {
        __half2 a2 = __floats2half2_rn(xv.x + accx, xv.y + accy);
        __half2 b2 = __floats2half2_rn(xv.x * accx, xv.y * accy);
        ash[w][lane] = *(unsigned*)&a2;
        bsh[w][lane] = *(unsigned*)&b2;
    }
    __syncthreads();

    float hres = 0.f;
    if constexpr (DOUT == DIN) {
        int o = lane;
        uint4 wg[DIN / 8], wb[DIN / 8];
        #pragma unroll
        for (int k = 0; k < DIN / 8; ++k) {
            wg[k] = *(const uint4*)(WT + wgOff + (size_t)(k * DOUT + o) * 8);
            wb[k] = *(const uint4*)(WT + wbOff + (size_t)(k * DOUT + o) * 8);
        }
        float ag = bgc[o], ab = bbi[o];
        #pragma unroll
        for (int k = 0; k < DIN / 8; ++k) {
            uint4 a4 = *(const uint4*)&ash[w][k * 4];
            uint4 b4 = *(const uint4*)&bsh[w][k * 4];
            ag = dot2(a4.x, wg[k].x, ag); ag = dot2(a4.y, wg[k].y, ag);
            ag = dot2(a4.z, wg[k].z, ag); ag = dot2(a4.w, wg[k].w, ag);
            ab = dot2(b4.x, wb[k].x, ab); ab = dot2(b4.y, wb[k].y, ab);
            ab = dot2(b4.z, wb[k].z, ab); ab = dot2(b4.w, wb[k].w, ab);
        }
        ag = ag > 0.f ? ag : 0.01f * ag;
        ab = ab > 0.f ? ab : 0.01f * ab;
        hres = ag + ab;
    } else {
        int o = lane & (DOUT - 1);
        bool gc = lane < DOUT;
        bool active = lane < 2 * DOUT;
        int woff2 = gc ? wgOff : wbOff;
        uint4 wr[DIN / 8];
        #pragma unroll
        for (int k = 0; k < DIN / 8; ++k)
            wr[k] = *(const uint4*)(WT + woff2 + (size_t)(k * DOUT + o) * 8);
        const unsigned* sp = gc ? &ash[w][0] : &bsh[w][0];
        float own = active ? (gc ? bgc[o] : bbi[o]) : 0.f;
        #pragma unroll
        for (int k = 0; k < DIN / 8; ++k) {
            uint4 s4 = *(const uint4*)(sp + k * 4);
            own = dot2(s4.x, wr[k].x, own); own = dot2(s4.y, wr[k].y, own);
            own = dot2(s4.z, wr[k].z, own); own = dot2(s4.w, wr[k].w, own);
        }
        own = own > 0.f ? own : 0.01f * own;
        float other = __shfl_xor(own, DOUT);
        hres = own + other;
    }

    float hq = (lane < DOUT) ? hres : 0.f;
    float ss = hq * hq;
    #pragma unroll
    for (int off = 32; off; off >>= 1) ss += __shfl_xor(ss, off);

    if (lane < DOUT) {
        float inv = 1.f / fmaxf(sqrtf(ss), 1e-12f);
        out[(size_t)n * OUT_D + cout + lane] = hres * inv;
    }
}

extern "C" void kernel_launch(void* const* d_in, const int* in_sizes, int n_in,
                              void* d_out, int out_size, void* d_ws, size_t ws_size,
                              hipStream_t stream) {
    const float* ue = (const float*)d_in[0];
    const float* ee = (const float*)d_in[1];
    const float* ev = (const float*)d_in[2];
    const int*   er = (const int*)d_in[3];
    const int*   ec = (const int*)d_in[4];
    float* out = (float*)d_out;

    unsigned long long* tmp    = (unsigned long long*)d_ws;     // CSR temp
    __half*             xh     = (__half*)d_ws;                 // after CSR
    unsigned int*       edges  = (unsigned int*)((char*)d_ws + 19200000);
    int*                cursor = (int*)((char*)d_ws + 28800000);
    int*                table  = (int*)((char*)d_ws + 29400000);
    int*                bsum   = (int*)((char*)d_ws + 30000000);
    __half*             WT     = (__half*)((char*)d_ws + 30100000);

    // ---- CSR via two-level bucket sort ----
    histP1_kernel<<<P1_BLOCKS, 256, 0, stream>>>(er, table);
    scanA_kernel<<<SCAN_BLKS, 1024, 0, stream>>>(table, bsum, TBL);
    scanB_kernel<<<1, 1024, 0, stream>>>(bsum, SCAN_BLKS);
    scanC_kernel<<<SCAN_BLKS, 1024, 0, stream>>>(table, bsum, TBL);
    scatterP1_kernel<<<P1_BLOCKS, 256, 0, stream>>>(ev, er, ec, table, tmp);
    pass2_kernel<<<NBKT, 512, 0, stream>>>(tmp, table, edges, cursor);

    // tmp dead; xh takes over the region
    init_x_kernel<<<(N_NODES * 16) / 256, 256, 0, stream>>>(ue, ee, out, xh);
    wt_kernel<<<52, 256, 0, stream>>>((const float*)d_in[5],  (const float*)d_in[7],
                                      (const float*)d_in[9],  (const float*)d_in[11],
                                      (const float*)d_in[13], (const float*)d_in[15], WT);

    const int GRID = N_NODES / 4;   // 37500

    // layer 0: DIN=64 DOUT=64, x at col 0, write col 64
    fused_layer_kernel<64, 64><<<GRID, 256, 0, stream>>>(cursor, edges, xh, out,
        WT, 0, 4096, (const float*)d_in[6], (const float*)d_in[8], 0, 64);
    conv_kernel<<<(N_NODES * 32) / 256, 256, 0, stream>>>(out + 64, xh, 64);

    // layer 1: DIN=64 DOUT=32, x at col 64, write col 128
    fused_layer_kernel<64, 32><<<GRID, 256, 0, stream>>>(cursor, edges, xh, out,
        WT, 8192, 10240, (const float*)d_in[10], (const float*)d_in[12], 64, 128);
    conv_kernel<<<(N_NODES * 16) / 256, 256, 0, stream>>>(out + 128, xh, 32);

    // layer 2: DIN=32 DOUT=16, x at col 128, write col 160
    fused_layer_kernel<32, 16><<<GRID, 256, 0, stream>>>(cursor, edges, xh, out,
        WT, 12288, 12800, (const float*)d_in[14], (const float*)d_in[16], 128, 160);
}